// Round 14
// baseline (86.576 us; speedup 1.0000x reference)
//
#include <hip/hip_runtime.h>
#include <hip/hip_bf16.h>
#include <cstdint>
#include <cmath>

#define N_PIX 4096
#define CH    128
#define DD    64
#define NBATCH 8
#define NT    32    // 4096 / 128 key-tiles

typedef unsigned short u16;
typedef __attribute__((ext_vector_type(8))) short bf8_t;
typedef __attribute__((ext_vector_type(4))) float f4_t;
typedef __attribute__((ext_vector_type(16))) float f16v;
typedef uint32_t u32x4 __attribute__((ext_vector_type(4)));
typedef uint32_t u32x2 __attribute__((ext_vector_type(2)));

#define L2E 1.44269504088896340736f

// Native 2^x (single v_exp_f32).
#if __has_builtin(__builtin_amdgcn_exp2f)
  #define EXP2(x) __builtin_amdgcn_exp2f(x)
#else
  #define EXP2(x) exp2f(x)
#endif

// Hardware bf16 convert (v_cvt[_pk]_bf16_f32, RNE).
__device__ __forceinline__ u16 f2b(float f) {
  return __builtin_bit_cast(u16, __float2bfloat16(f));
}
__device__ __forceinline__ float b2f(u16 h) {
  union { uint32_t u; float f; } v; v.u = ((uint32_t)h) << 16;
  return v.f;
}
__device__ __forceinline__ uint32_t pack2(float a, float b) {
  return (uint32_t)f2b(a) | ((uint32_t)f2b(b) << 16);
}
// 3-input max — shaped so clang can fuse to v_max3_f32 (T17).
__device__ __forceinline__ float max3f(float a, float b, float c) {
  return fmaxf(fmaxf(a, b), c);
}
__device__ __forceinline__ f4_t mfma16(bf8_t a, bf8_t b, f4_t c) {
  return __builtin_amdgcn_mfma_f32_16x16x32_bf16(a, b, c, 0, 0, 0);
}
__device__ __forceinline__ f16v mfma32(bf8_t a, bf8_t b, f16v c) {
  return __builtin_amdgcn_mfma_f32_32x32x16_bf16(a, b, c, 0, 0, 0);
}
// Compiler-modeled permlane32 swap. SAFE ONLY ON DISTINCT VALUES (R3/R6
// lesson: same-value operands degenerate to a self half-swap). Cross-half
// reduces use __shfl_xor(x,32).
__device__ __forceinline__ void pl32swap(uint32_t &a, uint32_t &b) {
  u32x2 r = __builtin_amdgcn_permlane32_swap(a, b, false, false);
  a = r[0];
  b = r[1];
}

// ---------------------------------------------------------------------------
// Kernel 0: one-shot weight convert to bf16 in workspace.
// wq layout (u16): [0,8192) = tw * log2(e) (row-major [o][c]),
// [8192,16384) = pw, [16384,24576) = gw, [24576,32768) = ow ([c][k]).
// Same f2b RNE + scale math as the in-proj converts -> bitwise identical.
// ---------------------------------------------------------------------------
__global__ __launch_bounds__(256) void wcvt_kernel(
    const float* __restrict__ tw, const float* __restrict__ pw,
    const float* __restrict__ gw, const float* __restrict__ ow,
    u16* __restrict__ wq) {
  int i = blockIdx.x * 256 + threadIdx.x;   // 0..32767
  float v;
  if (i < 8192)       v = tw[i] * L2E;
  else if (i < 16384) v = pw[i - 8192];
  else if (i < 24576) v = gw[i - 16384];
  else                v = ow[i - 24576];
  wq[i] = f2b(v);
}

// ---------------------------------------------------------------------------
// Kernel 1 (fallback): fused projections, weights converted in-kernel.
// theta pre-scaled by log2(e). theta_h[b][n][64], phi_h[b][n][64],
// gt_h[b][64][n] (bf16, bias included). (R10-verified.)
// ---------------------------------------------------------------------------
__global__ __launch_bounds__(256) void proj_kernel(
    const float* __restrict__ x,
    const float* __restrict__ tw, const float* __restrict__ tb,
    const float* __restrict__ pw, const float* __restrict__ pb,
    const float* __restrict__ gw, const float* __restrict__ gb,
    u16* __restrict__ theta_h, u16* __restrict__ phi_h, u16* __restrict__ gt_h) {
  __shared__ __align__(16) u16 xT[64][136];
  const int blk = blockIdx.x;
  const int b  = blk >> 6;
  const int n0 = (blk & 63) << 6;
  const int tid = threadIdx.x;

  #pragma unroll
  for (int i = 0; i < 8; ++i) {
    int idx = tid + i * 256;
    int px = (idx & 15) * 4;
    int c  = idx >> 4;
    float4 v = *(const float4*)(x + ((size_t)b * CH + c) * N_PIX + n0 + px);
    xT[px + 0][c] = f2b(v.x);
    xT[px + 1][c] = f2b(v.y);
    xT[px + 2][c] = f2b(v.z);
    xT[px + 3][c] = f2b(v.w);
  }
  __syncthreads();

  const int lane = tid & 63;
  const int w    = tid >> 6;
  const int l4   = lane >> 4, l15 = lane & 15;

  bf8_t bw[3][4];
  float bias[3];
  #pragma unroll
  for (int nt = 0; nt < 3; ++nt) {
    int op = 16 * (3 * w + nt) + l15;
    const float* wrow; float bv; float scl;
    if (op < 64)       { wrow = tw + op * CH;          bv = tb[op];        scl = L2E; }
    else if (op < 128) { wrow = pw + (op - 64) * CH;   bv = pb[op - 64];   scl = 1.f; }
    else               { wrow = gw + (op - 128) * CH;  bv = gb[op - 128];  scl = 1.f; }
    bias[nt] = bv * scl;
    #pragma unroll
    for (int ks = 0; ks < 4; ++ks) {
      const float* p = wrow + 32 * ks + l4 * 8;
      bf8_t v;
      #pragma unroll
      for (int j = 0; j < 8; ++j) v[j] = (short)f2b(p[j] * scl);
      bw[nt][ks] = v;
    }
  }

  f4_t acc[4][3];
  #pragma unroll
  for (int mt = 0; mt < 4; ++mt)
    #pragma unroll
    for (int nt = 0; nt < 3; ++nt) acc[mt][nt] = (f4_t){0.f, 0.f, 0.f, 0.f};

  #pragma unroll
  for (int mt = 0; mt < 4; ++mt) {
    #pragma unroll
    for (int ks = 0; ks < 4; ++ks) {
      bf8_t a = *(const bf8_t*)&xT[l15 + 16 * mt][32 * ks + l4 * 8];
      #pragma unroll
      for (int nt = 0; nt < 3; ++nt)
        acc[mt][nt] = mfma16(a, bw[nt][ks], acc[mt][nt]);
    }
  }

  #pragma unroll
  for (int nt = 0; nt < 3; ++nt) {
    int op = 16 * (3 * w + nt) + l15;
    #pragma unroll
    for (int mt = 0; mt < 4; ++mt) {
      #pragma unroll
      for (int r = 0; r < 4; ++r) {
        int q = n0 + 16 * mt + l4 * 4 + r;
        u16 h = f2b(acc[mt][nt][r] + bias[nt]);
        if (op < 64)       theta_h[((size_t)b * N_PIX + q) * DD + op] = h;
        else if (op < 128) phi_h[((size_t)b * N_PIX + q) * DD + (op - 64)] = h;
        else               gt_h[((size_t)b * DD + (op - 128)) * N_PIX + q] = h;
      }
    }
  }
}

// ---------------------------------------------------------------------------
// Kernel 1q: projections using pre-converted bf16 weights (wq). Replaces 96
// scalar fp32 loads+converts per thread with 12 x 16B bf8_t loads (L2-hit).
// ---------------------------------------------------------------------------
__global__ __launch_bounds__(256) void proj_kernel_q(
    const float* __restrict__ x,
    const float* __restrict__ tb, const float* __restrict__ pb,
    const float* __restrict__ gb, const u16* __restrict__ wq,
    u16* __restrict__ theta_h, u16* __restrict__ phi_h, u16* __restrict__ gt_h) {
  __shared__ __align__(16) u16 xT[64][136];
  const int blk = blockIdx.x;
  const int b  = blk >> 6;
  const int n0 = (blk & 63) << 6;
  const int tid = threadIdx.x;

  #pragma unroll
  for (int i = 0; i < 8; ++i) {
    int idx = tid + i * 256;
    int px = (idx & 15) * 4;
    int c  = idx >> 4;
    float4 v = *(const float4*)(x + ((size_t)b * CH + c) * N_PIX + n0 + px);
    xT[px + 0][c] = f2b(v.x);
    xT[px + 1][c] = f2b(v.y);
    xT[px + 2][c] = f2b(v.z);
    xT[px + 3][c] = f2b(v.w);
  }
  __syncthreads();

  const int lane = tid & 63;
  const int w    = tid >> 6;
  const int l4   = lane >> 4, l15 = lane & 15;

  bf8_t bw[3][4];
  float bias[3];
  #pragma unroll
  for (int nt = 0; nt < 3; ++nt) {
    int op = 16 * (3 * w + nt) + l15;
    float bv;
    if (op < 64)       bv = tb[op] * L2E;
    else if (op < 128) bv = pb[op - 64];
    else               bv = gb[op - 128];
    bias[nt] = bv;
    #pragma unroll
    for (int ks = 0; ks < 4; ++ks)
      bw[nt][ks] = *(const bf8_t*)(wq + (size_t)op * CH + 32 * ks + l4 * 8);
  }

  f4_t acc[4][3];
  #pragma unroll
  for (int mt = 0; mt < 4; ++mt)
    #pragma unroll
    for (int nt = 0; nt < 3; ++nt) acc[mt][nt] = (f4_t){0.f, 0.f, 0.f, 0.f};

  #pragma unroll
  for (int mt = 0; mt < 4; ++mt) {
    #pragma unroll
    for (int ks = 0; ks < 4; ++ks) {
      bf8_t a = *(const bf8_t*)&xT[l15 + 16 * mt][32 * ks + l4 * 8];
      #pragma unroll
      for (int nt = 0; nt < 3; ++nt)
        acc[mt][nt] = mfma16(a, bw[nt][ks], acc[mt][nt]);
    }
  }

  #pragma unroll
  for (int nt = 0; nt < 3; ++nt) {
    int op = 16 * (3 * w + nt) + l15;
    #pragma unroll
    for (int mt = 0; mt < 4; ++mt) {
      #pragma unroll
      for (int r = 0; r < 4; ++r) {
        int q = n0 + 16 * mt + l4 * 4 + r;
        u16 h = f2b(acc[mt][nt][r] + bias[nt]);
        if (op < 64)       theta_h[((size_t)b * N_PIX + q) * DD + op] = h;
        else if (op < 128) phi_h[((size_t)b * N_PIX + q) * DD + (op - 64)] = h;
        else               gt_h[((size_t)b * DD + (op - 128)) * N_PIX + q] = h;
      }
    }
  }
}

// ---------------------------------------------------------------------------
// Kernel 2: flash attention — EXACT R10 structure (verified 62.2µs):
// 32x32 MFMA, swapped QK^T, in-register P path, max3 tree + shfl cross-half
// max, defer-max (T13), ones-MFMA row-sum, setprio, unroll-2, 1-tile-ahead
// register staging into double-buffered XOR-swizzled LDS.
// (R8 destage, R12 2-deep reg prefetch, R13 global_load_lds all regressed.)
// ---------------------------------------------------------------------------
__global__ __launch_bounds__(512, 4) void attn_kernel(
    const u16* __restrict__ theta_h, const u16* __restrict__ phi_h,
    const u16* __restrict__ gt_h, u16* __restrict__ y_h) {
  __shared__ __align__(16) u16 smem[32768];   // 64 KiB: 2 bufs x (phi|gt)

  const int bid = blockIdx.x;                  // 512 blocks, 512 % 8 == 0
  const int lb  = (bid & 7) * 64 + (bid >> 3); // XCD swizzle: batch per XCD
  const int b   = lb >> 6;
  const int q0  = (lb & 63) << 6;
  const int tid = threadIdx.x;
  const int l   = tid & 63;
  const int w   = tid >> 6;
  const int qg  = w & 1;    // q-group (32 q)
  const int mh  = w >> 1;   // m-slice (32 of each 128-key tile)
  const int l31 = l & 31;
  const int hi  = l >> 5;

  // theta B-fragments (base-2-scaled): theta[q = q0+32qg+l31][k = 16kk+8hi..]
  bf8_t th[4];
  {
    const u16* trow = theta_h + ((size_t)b * N_PIX + q0 + 32 * qg + l31) * DD;
    #pragma unroll
    for (int kk = 0; kk < 4; ++kk)
      th[kk] = *(const bf8_t*)(trow + 16 * kk + 8 * hi);
  }

  // all-ones A fragment (bf16 1.0 = 0x3F80) for the row-sum MFMA
  const bf8_t onesA = __builtin_bit_cast(bf8_t,
      (u32x4){0x3F803F80u, 0x3F803F80u, 0x3F803F80u, 0x3F803F80u});

  f16v yacc[2];
  #pragma unroll
  for (int ot = 0; ot < 2; ++ot)
    #pragma unroll
    for (int r = 0; r < 16; ++r) yacc[ot][r] = 0.f;
  f16v y2;                       // row-sum accumulator; only y2[0] is consumed
  #pragma unroll
  for (int r = 0; r < 16; ++r) y2[r] = 0.f;
  float m_ = -1e30f;

  // ---- staging addresses (per thread: 2 phi chunks + 2 gt chunks of 16B) --
  const int pr  = tid >> 3, pc = tid & 7;
  const int go  = tid >> 4, gc = tid & 15;
  const u16* phA = phi_h + ((size_t)b * N_PIX + pr) * DD + pc * 8;
  const u16* gtA = gt_h + ((size_t)b * DD + go) * N_PIX + gc * 8;
  const int pO0 = pr * 64 + ((pc ^ (pr & 7)) << 3);
  const int pO1 = pO0 + 4096;
  const int gO0 = 8192 + go * 128 + ((gc ^ (go & 7)) << 3);
  const int gO1 = gO0 + 4096;

  uint4 v0, v1, v2, v3;
  #define LOADS(kb_) do {                                              \
    v0 = *(const uint4*)(phA + (size_t)(kb_) * 8192);                  \
    v1 = *(const uint4*)(phA + (size_t)(kb_) * 8192 + 4096);           \
    v2 = *(const uint4*)(gtA + (size_t)(kb_) * 128);                   \
    v3 = *(const uint4*)(gtA + (size_t)(kb_) * 128 + 32 * (size_t)N_PIX); \
  } while (0)
  #define WRITES(buf_) do {                                            \
    u16* base_ = smem + (buf_) * 16384;                                \
    *(uint4*)(base_ + pO0) = v0;                                       \
    *(uint4*)(base_ + pO1) = v1;                                       \
    *(uint4*)(base_ + gO0) = v2;                                       \
    *(uint4*)(base_ + gO1) = v3;                                       \
  } while (0)

  LOADS(0); WRITES(0);
  __syncthreads();

  const int prow  = 32 * mh + l31;
  const int pbase = prow * 64;
  const int pkey  = prow & 7;

  #pragma unroll 2
  for (int t = 0; t < NT; ++t) {
    const int cur = t & 1;
    if (t < NT - 1) LOADS(t + 1);
    const u16* pb = smem + cur * 16384;
    const u16* gb = pb + 8192;

    // ---- QK^T (swapped): ST[m][q], 4 x mfma32 over K=64 ------------------
    f16v st;
    #pragma unroll
    for (int r = 0; r < 16; ++r) st[r] = 0.f;
    __builtin_amdgcn_s_setprio(1);
    #pragma unroll
    for (int kk = 0; kk < 4; ++kk) {
      bf8_t a = *(const bf8_t*)(pb + pbase + (((2 * kk + hi) ^ pkey) << 3));
      st = mfma32(a, th[kk], st);
    }
    __builtin_amdgcn_s_setprio(0);

    // ---- max: max3 tree + cross-half shfl (verified) ---------------------
    float t0 = max3f(st[0],  st[1],  st[2]);
    float t1 = max3f(st[3],  st[4],  st[5]);
    float t2 = max3f(st[6],  st[7],  st[8]);
    float t3 = max3f(st[9],  st[10], st[11]);
    float t4 = max3f(st[12], st[13], st[14]);
    float pmax = fmaxf(max3f(t0, t1, t2), max3f(t3, t4, st[15]));
    pmax = fmaxf(pmax, __shfl_xor(pmax, 32));

    // ---- defer-max (T13): rescale only when running max grows > 2^8 ------
    if (!__all(pmax <= m_ + 8.f)) {
      float mn = fmaxf(m_, pmax);
      float sc = EXP2(m_ - mn);
      m_ = mn;
      y2[0] *= sc;                 // only y2[0] is ever read
      #pragma unroll
      for (int ot = 0; ot < 2; ++ot)
        #pragma unroll
        for (int r = 0; r < 16; ++r) yacc[ot][r] *= sc;
    }

    // ---- P = 2^(st - m) ---------------------------------------------------
    #pragma unroll
    for (int r = 0; r < 16; ++r) st[r] = EXP2(st[r] - m_);

    // ---- P -> PV B-fragments (hw cvt_pk + permlane swap, distinct) -------
    uint32_t c0 = pack2(st[0],  st[1]),  c1 = pack2(st[2],  st[3]);
    uint32_t c2 = pack2(st[4],  st[5]),  c3 = pack2(st[6],  st[7]);
    uint32_t c4 = pack2(st[8],  st[9]),  c5 = pack2(st[10], st[11]);
    uint32_t c6 = pack2(st[12], st[13]), c7 = pack2(st[14], st[15]);
    pl32swap(c0, c2); pl32swap(c1, c3);
    pl32swap(c4, c6); pl32swap(c5, c7);
    bf8_t pf0 = __builtin_bit_cast(bf8_t, (u32x4){c0, c1, c2, c3}); // m 0..15
    bf8_t pf1 = __builtin_bit_cast(bf8_t, (u32x4){c4, c5, c6, c7}); // m 16..31

    // ---- PV + row-sum: y^T[o][q] += gt[o][m].P^T[m][q]; y2 += 1.P^T ------
    __builtin_amdgcn_s_setprio(1);
    y2 = mfma32(onesA, pf0, y2);   // every row of y2 = sum_m P[m][q]
    y2 = mfma32(onesA, pf1, y2);
    #pragma unroll
    for (int ot = 0; ot < 2; ++ot) {
      int orow  = 32 * ot + l31;
      int obase = orow * 128;
      int okey  = orow & 7;
      bf8_t g0 = *(const bf8_t*)(gb + obase + ((((mh << 2) + hi)     ^ okey) << 3));
      yacc[ot] = mfma32(g0, pf0, yacc[ot]);
      bf8_t g1 = *(const bf8_t*)(gb + obase + ((((mh << 2) + 2 + hi) ^ okey) << 3));
      yacc[ot] = mfma32(g1, pf1, yacc[ot]);
    }
    __builtin_amdgcn_s_setprio(0);

    if (t < NT - 1) WRITES(cur ^ 1);
    __syncthreads();
  }
  #undef LOADS
  #undef WRITES

  // l_ = full m-slice row sum (halves already merged inside pf0/pf1)
  float l_ = y2[0];

  // ---- 4-way flash merge across m-slices (reuse smem) ---------------------
  #pragma unroll
  for (int ot = 0; ot < 2; ++ot)
    #pragma unroll
    for (int r = 0; r < 16; ++r) {
      int o = 32 * ot + (r & 3) + 8 * (r >> 2) + 4 * hi;
      smem[(((qg * 4 + mh) * 64 + o) << 5) + l31] = f2b(yacc[ot][r]);
    }
  float* ml = (float*)(smem + 16384);
  if (hi == 0) {
    ml[(qg * 4 + mh) * 64 + l31]      = m_;
    ml[(qg * 4 + mh) * 64 + 32 + l31] = l_;
  }
  __syncthreads();

  {
    const int qg2 = tid >> 8;
    const int rem = tid & 255;
    const int qq  = rem & 31;
    const int og  = rem >> 5;
    float mi[4], li[4];
    #pragma unroll
    for (int i = 0; i < 4; ++i) {
      mi[i] = ml[(qg2 * 4 + i) * 64 + qq];
      li[i] = ml[(qg2 * 4 + i) * 64 + 32 + qq];
    }
    float M = fmaxf(fmaxf(mi[0], mi[1]), fmaxf(mi[2], mi[3]));
    float e[4], L = 0.f;
    #pragma unroll
    for (int i = 0; i < 4; ++i) { e[i] = EXP2(mi[i] - M); L += li[i] * e[i]; }
    float invL = 1.0f / L;
    float acc[8];
    #pragma unroll
    for (int oo = 0; oo < 8; ++oo) {
      int o = og * 8 + oo;
      float a = 0.f;
      #pragma unroll
      for (int i = 0; i < 4; ++i)
        a += b2f(smem[(((qg2 * 4 + i) * 64 + o) << 5) + qq]) * e[i];
      acc[oo] = a * invL;
    }
    uint4 ov;
    ov.x = pack2(acc[0], acc[1]);
    ov.y = pack2(acc[2], acc[3]);
    ov.z = pack2(acc[4], acc[5]);
    ov.w = pack2(acc[6], acc[7]);
    *(uint4*)(y_h + ((size_t)b * N_PIX + q0 + 32 * qg2 + qq) * DD + og * 8) = ov;
  }
}

// ---------------------------------------------------------------------------
// Kernel 3 (fallback): out = out_w @ y + out_b + x, in-kernel weight convert.
// ---------------------------------------------------------------------------
__global__ __launch_bounds__(256) void outproj_kernel(
    const u16* __restrict__ y_h, const float* __restrict__ ow,
    const float* __restrict__ ob, const float* __restrict__ x,
    float* __restrict__ out) {
  __shared__ __align__(16) float ot[128][68];
  const int blk = blockIdx.x;
  const int b  = blk >> 6;
  const int n0 = (blk & 63) << 6;
  const int tid = threadIdx.x;
  const int lane = tid & 63;
  const int w    = tid >> 6;
  const int l4   = lane >> 4, l15 = lane & 15;

  bf8_t bw[2][2];
  float bias[2];
  #pragma unroll
  for (int nt = 0; nt < 2; ++nt) {
    int c = 16 * (2 * w + nt) + l15;
    bias[nt] = ob[c];
    #pragma unroll
    for (int ks = 0; ks < 2; ++ks) {
      const float* p = ow + c * DD + 32 * ks + l4 * 8;
      bf8_t v;
      #pragma unroll
      for (int j = 0; j < 8; ++j) v[j] = (short)f2b(p[j]);
      bw[nt][ks] = v;
    }
  }

  f4_t acc[4][2];
  #pragma unroll
  for (int mt = 0; mt < 4; ++mt)
    #pragma unroll
    for (int nt = 0; nt < 2; ++nt) acc[mt][nt] = (f4_t){0.f, 0.f, 0.f, 0.f};

  #pragma unroll
  for (int mt = 0; mt < 4; ++mt) {
    const u16* yr = y_h + ((size_t)b * N_PIX + n0 + 16 * mt + l15) * DD + l4 * 8;
    bf8_t a0 = *(const bf8_t*)yr;
    bf8_t a1 = *(const bf8_t*)(yr + 32);
    #pragma unroll
    for (int nt = 0; nt < 2; ++nt) {
      acc[mt][nt] = mfma16(a0, bw[nt][0], acc[mt][nt]);
      acc[mt][nt] = mfma16(a1, bw[nt][1], acc[mt][nt]);
    }
  }

  #pragma unroll
  for (int nt = 0; nt < 2; ++nt) {
    int c = 16 * (2 * w + nt) + l15;
    #pragma unroll
    for (int mt = 0; mt < 4; ++mt)
      #pragma unroll
      for (int r = 0; r < 4; ++r)
        ot[c][16 * mt + l4 * 4 + r] = acc[mt][nt][r] + bias[nt];
  }
  __syncthreads();

  #pragma unroll
  for (int i = 0; i < 8; ++i) {
    int idx = tid + i * 256;
    int px = (idx & 15) * 4;
    int c  = idx >> 4;
    size_t gi = ((size_t)b * CH + c) * N_PIX + n0 + px;
    float4 xv = *(const float4*)(x + gi);
    float4 o;
    o.x = ot[c][px + 0] + xv.x;
    o.y = ot[c][px + 1] + xv.y;
    o.z = ot[c][px + 2] + xv.z;
    o.w = ot[c][px + 3] + xv.w;
    *(float4*)(out + gi) = o;
  }
}

// ---------------------------------------------------------------------------
// Kernel 3q: out-projection using pre-converted bf16 ow (owq = wq + 24576).
// ---------------------------------------------------------------------------
__global__ __launch_bounds__(256) void outproj_kernel_q(
    const u16* __restrict__ y_h, const u16* __restrict__ owq,
    const float* __restrict__ ob, const float* __restrict__ x,
    float* __restrict__ out) {
  __shared__ __align__(16) float ot[128][68];
  const int blk = blockIdx.x;
  const int b  = blk >> 6;
  const int n0 = (blk & 63) << 6;
  const int tid = threadIdx.x;
  const int lane = tid & 63;
  const int w    = tid >> 6;
  const int l4   = lane >> 4, l15 = lane & 15;

  bf8_t bw[2][2];
  float bias[2];
  #pragma unroll
  for (int nt = 0; nt < 2; ++nt) {
    int c = 16 * (2 * w + nt) + l15;
    bias[nt] = ob[c];
    #pragma unroll
    for (int ks = 0; ks < 2; ++ks)
      bw[nt][ks] = *(const bf8_t*)(owq + c * DD + 32 * ks + l4 * 8);
  }

  f4_t acc[4][2];
  #pragma unroll
  for (int mt = 0; mt < 4; ++mt)
    #pragma unroll
    for (int nt = 0; nt < 2; ++nt) acc[mt][nt] = (f4_t){0.f, 0.f, 0.f, 0.f};

  #pragma unroll
  for (int mt = 0; mt < 4; ++mt) {
    const u16* yr = y_h + ((size_t)b * N_PIX + n0 + 16 * mt + l15) * DD + l4 * 8;
    bf8_t a0 = *(const bf8_t*)yr;
    bf8_t a1 = *(const bf8_t*)(yr + 32);
    #pragma unroll
    for (int nt = 0; nt < 2; ++nt) {
      acc[mt][nt] = mfma16(a0, bw[nt][0], acc[mt][nt]);
      acc[mt][nt] = mfma16(a1, bw[nt][1], acc[mt][nt]);
    }
  }

  #pragma unroll
  for (int nt = 0; nt < 2; ++nt) {
    int c = 16 * (2 * w + nt) + l15;
    #pragma unroll
    for (int mt = 0; mt < 4; ++mt)
      #pragma unroll
      for (int r = 0; r < 4; ++r)
        ot[c][16 * mt + l4 * 4 + r] = acc[mt][nt][r] + bias[nt];
  }
  __syncthreads();

  #pragma unroll
  for (int i = 0; i < 8; ++i) {
    int idx = tid + i * 256;
    int px = (idx & 15) * 4;
    int c  = idx >> 4;
    size_t gi = ((size_t)b * CH + c) * N_PIX + n0 + px;
    float4 xv = *(const float4*)(x + gi);
    float4 o;
    o.x = ot[c][px + 0] + xv.x;
    o.y = ot[c][px + 1] + xv.y;
    o.z = ot[c][px + 2] + xv.z;
    o.w = ot[c][px + 3] + xv.w;
    *(float4*)(out + gi) = o;
  }
}

extern "C" void kernel_launch(void* const* d_in, const int* in_sizes, int n_in,
                              void* d_out, int out_size, void* d_ws, size_t ws_size,
                              hipStream_t stream) {
  const float* x  = (const float*)d_in[0];
  const float* tw = (const float*)d_in[1];
  const float* tb = (const float*)d_in[2];
  const float* pw = (const float*)d_in[3];
  const float* pb = (const float*)d_in[4];
  const float* gw = (const float*)d_in[5];
  const float* gb = (const float*)d_in[6];
  const float* ow = (const float*)d_in[7];
  const float* ob = (const float*)d_in[8];
  float* out = (float*)d_out;

  const size_t sz = (size_t)NBATCH * N_PIX * DD;   // elems per bf16 tensor
  u16* theta_h = (u16*)d_ws;
  u16* phi_h   = theta_h + sz;
  u16* gt_h    = phi_h + sz;
  u16* y_h     = gt_h + sz;
  u16* wq      = y_h + sz;                          // +64 KB weight cache

  const size_t need = (4 * sz + 32768) * sizeof(u16);
  if (ws_size >= need) {
    wcvt_kernel<<<128, 256, 0, stream>>>(tw, pw, gw, ow, wq);
    proj_kernel_q<<<512, 256, 0, stream>>>(x, tb, pb, gb, wq,
                                           theta_h, phi_h, gt_h);
    attn_kernel<<<512, 512, 0, stream>>>(theta_h, phi_h, gt_h, y_h);
    outproj_kernel_q<<<512, 256, 0, stream>>>(y_h, wq + 24576, ob, x, out);
  } else {
    proj_kernel<<<512, 256, 0, stream>>>(x, tw, tb, pw, pb, gw, gb,
                                         theta_h, phi_h, gt_h);
    attn_kernel<<<512, 512, 0, stream>>>(theta_h, phi_h, gt_h, y_h);
    outproj_kernel<<<512, 256, 0, stream>>>(y_h, ow, ob, x, out);
  }
}

// Round 15
// 79.938 us; speedup vs baseline: 1.0830x; 1.0830x over previous
//
#include <hip/hip_runtime.h>
#include <hip/hip_bf16.h>
#include <cstdint>
#include <cmath>

#define N_PIX 4096
#define CH    128
#define DD    64
#define NBATCH 8
#define NT    32    // 4096 / 128 key-tiles

typedef unsigned short u16;
typedef __attribute__((ext_vector_type(8))) short bf8_t;
typedef __attribute__((ext_vector_type(4))) float f4_t;
typedef __attribute__((ext_vector_type(16))) float f16v;
typedef uint32_t u32x4 __attribute__((ext_vector_type(4)));
typedef uint32_t u32x2 __attribute__((ext_vector_type(2)));

#define L2E 1.44269504088896340736f

// Native 2^x (single v_exp_f32).
#if __has_builtin(__builtin_amdgcn_exp2f)
  #define EXP2(x) __builtin_amdgcn_exp2f(x)
#else
  #define EXP2(x) exp2f(x)
#endif

// Hardware bf16 convert (v_cvt[_pk]_bf16_f32, RNE).
__device__ __forceinline__ u16 f2b(float f) {
  return __builtin_bit_cast(u16, __float2bfloat16(f));
}
__device__ __forceinline__ float b2f(u16 h) {
  union { uint32_t u; float f; } v; v.u = ((uint32_t)h) << 16;
  return v.f;
}
__device__ __forceinline__ uint32_t pack2(float a, float b) {
  return (uint32_t)f2b(a) | ((uint32_t)f2b(b) << 16);
}
// 3-input max — shaped so clang can fuse to v_max3_f32 (T17).
__device__ __forceinline__ float max3f(float a, float b, float c) {
  return fmaxf(fmaxf(a, b), c);
}
__device__ __forceinline__ f4_t mfma16(bf8_t a, bf8_t b, f4_t c) {
  return __builtin_amdgcn_mfma_f32_16x16x32_bf16(a, b, c, 0, 0, 0);
}
__device__ __forceinline__ f16v mfma32(bf8_t a, bf8_t b, f16v c) {
  return __builtin_amdgcn_mfma_f32_32x32x16_bf16(a, b, c, 0, 0, 0);
}
// Compiler-modeled permlane32 swap. SAFE ONLY ON DISTINCT VALUES (R3/R6
// lesson: same-value operands degenerate to a self half-swap). Cross-half
// reduces use __shfl_xor(x,32).
__device__ __forceinline__ void pl32swap(uint32_t &a, uint32_t &b) {
  u32x2 r = __builtin_amdgcn_permlane32_swap(a, b, false, false);
  a = r[0];
  b = r[1];
}

// ---------------------------------------------------------------------------
// Kernel 1: fused projections (R9-verified form, in-kernel weight convert).
// theta pre-scaled by log2(e). theta_h[b][n][64], phi_h[b][n][64],
// gt_h[b][64][n] (bf16, bias included).
// ---------------------------------------------------------------------------
__global__ __launch_bounds__(256) void proj_kernel(
    const float* __restrict__ x,
    const float* __restrict__ tw, const float* __restrict__ tb,
    const float* __restrict__ pw, const float* __restrict__ pb,
    const float* __restrict__ gw, const float* __restrict__ gb,
    u16* __restrict__ theta_h, u16* __restrict__ phi_h, u16* __restrict__ gt_h) {
  __shared__ __align__(16) u16 xT[64][136];
  const int blk = blockIdx.x;
  const int b  = blk >> 6;
  const int n0 = (blk & 63) << 6;
  const int tid = threadIdx.x;

  #pragma unroll
  for (int i = 0; i < 8; ++i) {
    int idx = tid + i * 256;
    int px = (idx & 15) * 4;
    int c  = idx >> 4;
    float4 v = *(const float4*)(x + ((size_t)b * CH + c) * N_PIX + n0 + px);
    xT[px + 0][c] = f2b(v.x);
    xT[px + 1][c] = f2b(v.y);
    xT[px + 2][c] = f2b(v.z);
    xT[px + 3][c] = f2b(v.w);
  }
  __syncthreads();

  const int lane = tid & 63;
  const int w    = tid >> 6;
  const int l4   = lane >> 4, l15 = lane & 15;

  bf8_t bw[3][4];
  float bias[3];
  #pragma unroll
  for (int nt = 0; nt < 3; ++nt) {
    int op = 16 * (3 * w + nt) + l15;
    const float* wrow; float bv; float scl;
    if (op < 64)       { wrow = tw + op * CH;          bv = tb[op];        scl = L2E; }
    else if (op < 128) { wrow = pw + (op - 64) * CH;   bv = pb[op - 64];   scl = 1.f; }
    else               { wrow = gw + (op - 128) * CH;  bv = gb[op - 128];  scl = 1.f; }
    bias[nt] = bv * scl;
    #pragma unroll
    for (int ks = 0; ks < 4; ++ks) {
      const float* p = wrow + 32 * ks + l4 * 8;
      bf8_t v;
      #pragma unroll
      for (int j = 0; j < 8; ++j) v[j] = (short)f2b(p[j] * scl);
      bw[nt][ks] = v;
    }
  }

  f4_t acc[4][3];
  #pragma unroll
  for (int mt = 0; mt < 4; ++mt)
    #pragma unroll
    for (int nt = 0; nt < 3; ++nt) acc[mt][nt] = (f4_t){0.f, 0.f, 0.f, 0.f};

  #pragma unroll
  for (int mt = 0; mt < 4; ++mt) {
    #pragma unroll
    for (int ks = 0; ks < 4; ++ks) {
      bf8_t a = *(const bf8_t*)&xT[l15 + 16 * mt][32 * ks + l4 * 8];
      #pragma unroll
      for (int nt = 0; nt < 3; ++nt)
        acc[mt][nt] = mfma16(a, bw[nt][ks], acc[mt][nt]);
    }
  }

  #pragma unroll
  for (int nt = 0; nt < 3; ++nt) {
    int op = 16 * (3 * w + nt) + l15;
    #pragma unroll
    for (int mt = 0; mt < 4; ++mt) {
      #pragma unroll
      for (int r = 0; r < 4; ++r) {
        int q = n0 + 16 * mt + l4 * 4 + r;
        u16 h = f2b(acc[mt][nt][r] + bias[nt]);
        if (op < 64)       theta_h[((size_t)b * N_PIX + q) * DD + op] = h;
        else if (op < 128) phi_h[((size_t)b * N_PIX + q) * DD + (op - 64)] = h;
        else               gt_h[((size_t)b * DD + (op - 128)) * N_PIX + q] = h;
      }
    }
  }
}

// ---------------------------------------------------------------------------
// Kernel 2: flash attention + FUSED out-projection epilogue.
// Main loop = EXACT R10 structure (verified 62.2µs). Epilogue: the merged
// y[64 q][64 o] tile goes to a padded LDS buffer (not global), then an 8-wave
// 128x64x64 GEMM computes out[c][q] = ow[c][:]·y[q][:] + ob[c] + x[c][q]
// directly — the y_h round-trip and the outproj kernel are deleted.
// ---------------------------------------------------------------------------
__global__ __launch_bounds__(512, 4) void attn_kernel(
    const u16* __restrict__ theta_h, const u16* __restrict__ phi_h,
    const u16* __restrict__ gt_h,
    const float* __restrict__ ow, const float* __restrict__ ob,
    const float* __restrict__ x, float* __restrict__ out) {
  __shared__ __align__(16) u16 smem[32768];   // 64 KiB

  const int bid = blockIdx.x;                  // 512 blocks, 512 % 8 == 0
  const int lb  = (bid & 7) * 64 + (bid >> 3); // XCD swizzle: batch per XCD
  const int b   = lb >> 6;
  const int q0  = (lb & 63) << 6;
  const int tid = threadIdx.x;
  const int l   = tid & 63;
  const int w   = tid >> 6;
  const int qg  = w & 1;    // q-group (32 q)
  const int mh  = w >> 1;   // m-slice (32 of each 128-key tile)
  const int l31 = l & 31;
  const int hi  = l >> 5;

  // theta B-fragments (base-2-scaled): theta[q = q0+32qg+l31][k = 16kk+8hi..]
  bf8_t th[4];
  {
    const u16* trow = theta_h + ((size_t)b * N_PIX + q0 + 32 * qg + l31) * DD;
    #pragma unroll
    for (int kk = 0; kk < 4; ++kk)
      th[kk] = *(const bf8_t*)(trow + 16 * kk + 8 * hi);
  }

  // all-ones A fragment (bf16 1.0 = 0x3F80) for the row-sum MFMA
  const bf8_t onesA = __builtin_bit_cast(bf8_t,
      (u32x4){0x3F803F80u, 0x3F803F80u, 0x3F803F80u, 0x3F803F80u});

  f16v yacc[2];
  #pragma unroll
  for (int ot = 0; ot < 2; ++ot)
    #pragma unroll
    for (int r = 0; r < 16; ++r) yacc[ot][r] = 0.f;
  f16v y2;                       // row-sum accumulator; only y2[0] is consumed
  #pragma unroll
  for (int r = 0; r < 16; ++r) y2[r] = 0.f;
  float m_ = -1e30f;

  // ---- staging addresses (per thread: 2 phi chunks + 2 gt chunks of 16B) --
  const int pr  = tid >> 3, pc = tid & 7;
  const int go  = tid >> 4, gc = tid & 15;
  const u16* phA = phi_h + ((size_t)b * N_PIX + pr) * DD + pc * 8;
  const u16* gtA = gt_h + ((size_t)b * DD + go) * N_PIX + gc * 8;
  const int pO0 = pr * 64 + ((pc ^ (pr & 7)) << 3);
  const int pO1 = pO0 + 4096;
  const int gO0 = 8192 + go * 128 + ((gc ^ (go & 7)) << 3);
  const int gO1 = gO0 + 4096;

  uint4 v0, v1, v2, v3;
  #define LOADS(kb_) do {                                              \
    v0 = *(const uint4*)(phA + (size_t)(kb_) * 8192);                  \
    v1 = *(const uint4*)(phA + (size_t)(kb_) * 8192 + 4096);           \
    v2 = *(const uint4*)(gtA + (size_t)(kb_) * 128);                   \
    v3 = *(const uint4*)(gtA + (size_t)(kb_) * 128 + 32 * (size_t)N_PIX); \
  } while (0)
  #define WRITES(buf_) do {                                            \
    u16* base_ = smem + (buf_) * 16384;                                \
    *(uint4*)(base_ + pO0) = v0;                                       \
    *(uint4*)(base_ + pO1) = v1;                                       \
    *(uint4*)(base_ + gO0) = v2;                                       \
    *(uint4*)(base_ + gO1) = v3;                                       \
  } while (0)

  LOADS(0); WRITES(0);
  __syncthreads();

  const int prow  = 32 * mh + l31;
  const int pbase = prow * 64;
  const int pkey  = prow & 7;

  #pragma unroll 2
  for (int t = 0; t < NT; ++t) {
    const int cur = t & 1;
    if (t < NT - 1) LOADS(t + 1);
    const u16* pb = smem + cur * 16384;
    const u16* gb = pb + 8192;

    // ---- QK^T (swapped): ST[m][q], 4 x mfma32 over K=64 ------------------
    f16v st;
    #pragma unroll
    for (int r = 0; r < 16; ++r) st[r] = 0.f;
    __builtin_amdgcn_s_setprio(1);
    #pragma unroll
    for (int kk = 0; kk < 4; ++kk) {
      bf8_t a = *(const bf8_t*)(pb + pbase + (((2 * kk + hi) ^ pkey) << 3));
      st = mfma32(a, th[kk], st);
    }
    __builtin_amdgcn_s_setprio(0);

    // ---- max: max3 tree + cross-half shfl (verified) ---------------------
    float t0 = max3f(st[0],  st[1],  st[2]);
    float t1 = max3f(st[3],  st[4],  st[5]);
    float t2 = max3f(st[6],  st[7],  st[8]);
    float t3 = max3f(st[9],  st[10], st[11]);
    float t4 = max3f(st[12], st[13], st[14]);
    float pmax = fmaxf(max3f(t0, t1, t2), max3f(t3, t4, st[15]));
    pmax = fmaxf(pmax, __shfl_xor(pmax, 32));

    // ---- defer-max (T13): rescale only when running max grows > 2^8 ------
    if (!__all(pmax <= m_ + 8.f)) {
      float mn = fmaxf(m_, pmax);
      float sc = EXP2(m_ - mn);
      m_ = mn;
      y2[0] *= sc;                 // only y2[0] is ever read
      #pragma unroll
      for (int ot = 0; ot < 2; ++ot)
        #pragma unroll
        for (int r = 0; r < 16; ++r) yacc[ot][r] *= sc;
    }

    // ---- P = 2^(st - m) ---------------------------------------------------
    #pragma unroll
    for (int r = 0; r < 16; ++r) st[r] = EXP2(st[r] - m_);

    // ---- P -> PV B-fragments (hw cvt_pk + permlane swap, distinct) -------
    uint32_t c0 = pack2(st[0],  st[1]),  c1 = pack2(st[2],  st[3]);
    uint32_t c2 = pack2(st[4],  st[5]),  c3 = pack2(st[6],  st[7]);
    uint32_t c4 = pack2(st[8],  st[9]),  c5 = pack2(st[10], st[11]);
    uint32_t c6 = pack2(st[12], st[13]), c7 = pack2(st[14], st[15]);
    pl32swap(c0, c2); pl32swap(c1, c3);
    pl32swap(c4, c6); pl32swap(c5, c7);
    bf8_t pf0 = __builtin_bit_cast(bf8_t, (u32x4){c0, c1, c2, c3}); // m 0..15
    bf8_t pf1 = __builtin_bit_cast(bf8_t, (u32x4){c4, c5, c6, c7}); // m 16..31

    // ---- PV + row-sum: y^T[o][q] += gt[o][m].P^T[m][q]; y2 += 1.P^T ------
    __builtin_amdgcn_s_setprio(1);
    y2 = mfma32(onesA, pf0, y2);   // every row of y2 = sum_m P[m][q]
    y2 = mfma32(onesA, pf1, y2);
    #pragma unroll
    for (int ot = 0; ot < 2; ++ot) {
      int orow  = 32 * ot + l31;
      int obase = orow * 128;
      int okey  = orow & 7;
      bf8_t g0 = *(const bf8_t*)(gb + obase + ((((mh << 2) + hi)     ^ okey) << 3));
      yacc[ot] = mfma32(g0, pf0, yacc[ot]);
      bf8_t g1 = *(const bf8_t*)(gb + obase + ((((mh << 2) + 2 + hi) ^ okey) << 3));
      yacc[ot] = mfma32(g1, pf1, yacc[ot]);
    }
    __builtin_amdgcn_s_setprio(0);

    if (t < NT - 1) WRITES(cur ^ 1);
    __syncthreads();
  }
  #undef LOADS
  #undef WRITES

  // l_ = full m-slice row sum (halves already merged inside pf0/pf1)
  float l_ = y2[0];

  // ---- 4-way flash merge across m-slices (reuse smem) ---------------------
  // ypart: [0,16384) u16 ; ml: [16384,17408) ; y_lds: [17408, 22016) pitch 72
  #pragma unroll
  for (int ot = 0; ot < 2; ++ot)
    #pragma unroll
    for (int r = 0; r < 16; ++r) {
      int o = 32 * ot + (r & 3) + 8 * (r >> 2) + 4 * hi;
      smem[(((qg * 4 + mh) * 64 + o) << 5) + l31] = f2b(yacc[ot][r]);
    }
  float* ml = (float*)(smem + 16384);
  if (hi == 0) {
    ml[(qg * 4 + mh) * 64 + l31]      = m_;
    ml[(qg * 4 + mh) * 64 + 32 + l31] = l_;
  }
  __syncthreads();

  u16* y_lds = smem + 17408;   // [64 q][72 pitch] bf16
  {
    const int qg2 = tid >> 8;
    const int rem = tid & 255;
    const int qq  = rem & 31;
    const int og  = rem >> 5;
    float mi[4], li[4];
    #pragma unroll
    for (int i = 0; i < 4; ++i) {
      mi[i] = ml[(qg2 * 4 + i) * 64 + qq];
      li[i] = ml[(qg2 * 4 + i) * 64 + 32 + qq];
    }
    float M = fmaxf(fmaxf(mi[0], mi[1]), fmaxf(mi[2], mi[3]));
    float e[4], L = 0.f;
    #pragma unroll
    for (int i = 0; i < 4; ++i) { e[i] = EXP2(mi[i] - M); L += li[i] * e[i]; }
    float invL = 1.0f / L;
    float acc[8];
    #pragma unroll
    for (int oo = 0; oo < 8; ++oo) {
      int o = og * 8 + oo;
      float a = 0.f;
      #pragma unroll
      for (int i = 0; i < 4; ++i)
        a += b2f(smem[(((qg2 * 4 + i) * 64 + o) << 5) + qq]) * e[i];
      acc[oo] = a * invL;
    }
    uint4 ov;
    ov.x = pack2(acc[0], acc[1]);
    ov.y = pack2(acc[2], acc[3]);
    ov.z = pack2(acc[4], acc[5]);
    ov.w = pack2(acc[6], acc[7]);
    *(uint4*)(y_lds + (32 * qg2 + qq) * 72 + og * 8) = ov;   // LDS, not global
  }
  __syncthreads();

  // ---- fused out-projection: out[c][n0+q] = ow[c][:]·y[q][:] + ob[c] + x --
  // 8 waves = 4 c-tiles x 2 q-tiles; per wave one 32x32 tile over K=64.
  {
    const int ct = w & 3;          // c base = 32*ct
    const int qt = w >> 2;         // q base = 32*qt
    f16v oacc;
    #pragma unroll
    for (int r = 0; r < 16; ++r) oacc[r] = 0.f;
    #pragma unroll
    for (int kk = 0; kk < 4; ++kk) {
      // A[i=c][k=o]: lane row c = 32ct+l31, k = 16kk+8hi+e (fp32 -> bf16)
      const float* wp = ow + (size_t)(32 * ct + l31) * DD + 16 * kk + 8 * hi;
      bf8_t av;
      #pragma unroll
      for (int j = 0; j < 8; ++j) av[j] = (short)f2b(wp[j]);
      // B[k=o][j=q] = y[q][o]: lane col q = 32qt+l31, same k slice
      bf8_t bv = *(const bf8_t*)(y_lds + (32 * qt + l31) * 72 + 16 * kk + 8 * hi);
      oacc = mfma32(av, bv, oacc);
    }
    // C layout: col q = l31, row c = (r&3)+8*(r>>2)+4*hi (+32ct)
    #pragma unroll
    for (int r = 0; r < 16; ++r) {
      int c = 32 * ct + (r & 3) + 8 * (r >> 2) + 4 * hi;
      size_t gi = ((size_t)b * CH + c) * N_PIX + q0 + 32 * qt + l31;
      out[gi] = oacc[r] + ob[c] + x[gi];
    }
  }
}

extern "C" void kernel_launch(void* const* d_in, const int* in_sizes, int n_in,
                              void* d_out, int out_size, void* d_ws, size_t ws_size,
                              hipStream_t stream) {
  const float* x  = (const float*)d_in[0];
  const float* tw = (const float*)d_in[1];
  const float* tb = (const float*)d_in[2];
  const float* pw = (const float*)d_in[3];
  const float* pb = (const float*)d_in[4];
  const float* gw = (const float*)d_in[5];
  const float* gb = (const float*)d_in[6];
  const float* ow = (const float*)d_in[7];
  const float* ob = (const float*)d_in[8];
  float* out = (float*)d_out;

  const size_t sz = (size_t)NBATCH * N_PIX * DD;   // elems per bf16 tensor
  u16* theta_h = (u16*)d_ws;
  u16* phi_h   = theta_h + sz;
  u16* gt_h    = phi_h + sz;

  proj_kernel<<<512, 256, 0, stream>>>(x, tw, tb, pw, pb, gw, gb,
                                       theta_h, phi_h, gt_h);
  attn_kernel<<<512, 512, 0, stream>>>(theta_h, phi_h, gt_h, ow, ob, x, out);
}

// Round 16
// 78.756 us; speedup vs baseline: 1.0993x; 1.0150x over previous
//
#include <hip/hip_runtime.h>
#include <hip/hip_bf16.h>
#include <cstdint>
#include <cmath>

#define N_PIX 4096
#define CH    128
#define DD    64
#define NBATCH 8
#define NT    32    // 4096 / 128 key-tiles

typedef unsigned short u16;
typedef __attribute__((ext_vector_type(8))) short bf8_t;
typedef __attribute__((ext_vector_type(4))) float f4_t;
typedef __attribute__((ext_vector_type(16))) float f16v;
typedef uint32_t u32x4 __attribute__((ext_vector_type(4)));
typedef uint32_t u32x2 __attribute__((ext_vector_type(2)));

#define L2E 1.44269504088896340736f

// Native 2^x (single v_exp_f32).
#if __has_builtin(__builtin_amdgcn_exp2f)
  #define EXP2(x) __builtin_amdgcn_exp2f(x)
#else
  #define EXP2(x) exp2f(x)
#endif

// Hardware bf16 convert (v_cvt[_pk]_bf16_f32, RNE).
__device__ __forceinline__ u16 f2b(float f) {
  return __builtin_bit_cast(u16, __float2bfloat16(f));
}
__device__ __forceinline__ float b2f(u16 h) {
  union { uint32_t u; float f; } v; v.u = ((uint32_t)h) << 16;
  return v.f;
}
__device__ __forceinline__ uint32_t pack2(float a, float b) {
  return (uint32_t)f2b(a) | ((uint32_t)f2b(b) << 16);
}
// 3-input max — shaped so clang can fuse to v_max3_f32 (T17).
__device__ __forceinline__ float max3f(float a, float b, float c) {
  return fmaxf(fmaxf(a, b), c);
}
__device__ __forceinline__ f4_t mfma16(bf8_t a, bf8_t b, f4_t c) {
  return __builtin_amdgcn_mfma_f32_16x16x32_bf16(a, b, c, 0, 0, 0);
}
__device__ __forceinline__ f16v mfma32(bf8_t a, bf8_t b, f16v c) {
  return __builtin_amdgcn_mfma_f32_32x32x16_bf16(a, b, c, 0, 0, 0);
}
// Compiler-modeled permlane32 swap. SAFE ONLY ON DISTINCT VALUES (R3/R6
// lesson: same-value operands degenerate to a self half-swap). Cross-half
// reduces use __shfl_xor(x,32).
__device__ __forceinline__ void pl32swap(uint32_t &a, uint32_t &b) {
  u32x2 r = __builtin_amdgcn_permlane32_swap(a, b, false, false);
  a = r[0];
  b = r[1];
}

// ---------------------------------------------------------------------------
// Kernel 1: fused projections. theta pre-scaled by log2(e). Outputs
// theta_h[b][n][64], phi_h[b][n][64], gt_h[b][64][n] (bf16, bias included).
// NEW: epilogue bounces acc through LDS ([64 q][200] pitch, 16B-aligned rows)
// so ALL global stores are uint4 (48 scalar 2B stores/thread -> 6 vector
// stores; kills partial-cache-line write amplification).
// ---------------------------------------------------------------------------
__global__ __launch_bounds__(256) void proj_kernel(
    const float* __restrict__ x,
    const float* __restrict__ tw, const float* __restrict__ tb,
    const float* __restrict__ pw, const float* __restrict__ pb,
    const float* __restrict__ gw, const float* __restrict__ gb,
    u16* __restrict__ theta_h, u16* __restrict__ phi_h, u16* __restrict__ gt_h) {
  __shared__ __align__(16) u16 smem[12800];   // 25.6 KB: xT(pitch136) / yO(pitch200)
  const int blk = blockIdx.x;
  const int b  = blk >> 6;
  const int n0 = (blk & 63) << 6;
  const int tid = threadIdx.x;

  // stage x tile [128 c][64 px] -> xT[px][c] (pitch 136, rows 16B-aligned)
  #pragma unroll
  for (int i = 0; i < 8; ++i) {
    int idx = tid + i * 256;
    int px = (idx & 15) * 4;
    int c  = idx >> 4;
    float4 v = *(const float4*)(x + ((size_t)b * CH + c) * N_PIX + n0 + px);
    smem[(px + 0) * 136 + c] = f2b(v.x);
    smem[(px + 1) * 136 + c] = f2b(v.y);
    smem[(px + 2) * 136 + c] = f2b(v.z);
    smem[(px + 3) * 136 + c] = f2b(v.w);
  }
  __syncthreads();

  const int lane = tid & 63;
  const int w    = tid >> 6;
  const int l4   = lane >> 4, l15 = lane & 15;

  bf8_t bw[3][4];
  float bias[3];
  #pragma unroll
  for (int nt = 0; nt < 3; ++nt) {
    int op = 16 * (3 * w + nt) + l15;
    const float* wrow; float bv; float scl;
    if (op < 64)       { wrow = tw + op * CH;          bv = tb[op];        scl = L2E; }
    else if (op < 128) { wrow = pw + (op - 64) * CH;   bv = pb[op - 64];   scl = 1.f; }
    else               { wrow = gw + (op - 128) * CH;  bv = gb[op - 128];  scl = 1.f; }
    bias[nt] = bv * scl;
    #pragma unroll
    for (int ks = 0; ks < 4; ++ks) {
      const float* p = wrow + 32 * ks + l4 * 8;
      bf8_t v;
      #pragma unroll
      for (int j = 0; j < 8; ++j) v[j] = (short)f2b(p[j] * scl);
      bw[nt][ks] = v;
    }
  }

  f4_t acc[4][3];
  #pragma unroll
  for (int mt = 0; mt < 4; ++mt)
    #pragma unroll
    for (int nt = 0; nt < 3; ++nt) acc[mt][nt] = (f4_t){0.f, 0.f, 0.f, 0.f};

  #pragma unroll
  for (int mt = 0; mt < 4; ++mt) {
    #pragma unroll
    for (int ks = 0; ks < 4; ++ks) {
      bf8_t a = *(const bf8_t*)&smem[(l15 + 16 * mt) * 136 + 32 * ks + l4 * 8];
      #pragma unroll
      for (int nt = 0; nt < 3; ++nt)
        acc[mt][nt] = mfma16(a, bw[nt][ks], acc[mt][nt]);
    }
  }
  __syncthreads();   // all xT reads done; reuse smem as yO[64][200]

  // write acc -> yO[q_local][op] (bf16, bias added)
  #pragma unroll
  for (int nt = 0; nt < 3; ++nt) {
    int op = 16 * (3 * w + nt) + l15;
    #pragma unroll
    for (int mt = 0; mt < 4; ++mt) {
      #pragma unroll
      for (int r = 0; r < 4; ++r) {
        int ql = 16 * mt + l4 * 4 + r;
        smem[ql * 200 + op] = f2b(acc[mt][nt][r] + bias[nt]);
      }
    }
  }
  __syncthreads();

  // theta/phi: full-row uint4 copies (coalesced, whole cache lines)
  #pragma unroll
  for (int i = 0; i < 4; ++i) {
    int idx = tid + i * 256;            // 0..1023 = 64 q x 16 chunks
    int q  = idx >> 4;
    int ch = idx & 15;
    uint4 v = *(const uint4*)&smem[q * 200 + ch * 8];
    if (ch < 8)
      *(uint4*)(theta_h + ((size_t)b * N_PIX + n0 + q) * DD + ch * 8) = v;
    else
      *(uint4*)(phi_h + ((size_t)b * N_PIX + n0 + q) * DD + (ch - 8) * 8) = v;
  }
  // gt: column gather + pack -> uint4 stores along q
  #pragma unroll
  for (int i = 0; i < 2; ++i) {
    int idx = tid + i * 256;            // 0..511 = 64 o x 8 q-octets
    int o = idx >> 3;
    int j = idx & 7;
    uint4 v;
    uint32_t* vp = (uint32_t*)&v;
    #pragma unroll
    for (int k = 0; k < 4; ++k) {
      u16 lo = smem[(8 * j + 2 * k) * 200 + 128 + o];
      u16 hi = smem[(8 * j + 2 * k + 1) * 200 + 128 + o];
      vp[k] = (uint32_t)lo | ((uint32_t)hi << 16);
    }
    *(uint4*)(gt_h + ((size_t)b * DD + o) * N_PIX + n0 + 8 * j) = v;
  }
}

// ---------------------------------------------------------------------------
// Kernel 2: flash attention + FUSED out-projection epilogue (R15-verified,
// byte-identical). Main loop = R10 structure; epilogue GEMMs y (in LDS)
// against ow and writes out = ow·y + ob + x directly.
// ---------------------------------------------------------------------------
__global__ __launch_bounds__(512, 4) void attn_kernel(
    const u16* __restrict__ theta_h, const u16* __restrict__ phi_h,
    const u16* __restrict__ gt_h,
    const float* __restrict__ ow, const float* __restrict__ ob,
    const float* __restrict__ x, float* __restrict__ out) {
  __shared__ __align__(16) u16 smem[32768];   // 64 KiB

  const int bid = blockIdx.x;                  // 512 blocks, 512 % 8 == 0
  const int lb  = (bid & 7) * 64 + (bid >> 3); // XCD swizzle: batch per XCD
  const int b   = lb >> 6;
  const int q0  = (lb & 63) << 6;
  const int tid = threadIdx.x;
  const int l   = tid & 63;
  const int w   = tid >> 6;
  const int qg  = w & 1;    // q-group (32 q)
  const int mh  = w >> 1;   // m-slice (32 of each 128-key tile)
  const int l31 = l & 31;
  const int hi  = l >> 5;

  // theta B-fragments (base-2-scaled): theta[q = q0+32qg+l31][k = 16kk+8hi..]
  bf8_t th[4];
  {
    const u16* trow = theta_h + ((size_t)b * N_PIX + q0 + 32 * qg + l31) * DD;
    #pragma unroll
    for (int kk = 0; kk < 4; ++kk)
      th[kk] = *(const bf8_t*)(trow + 16 * kk + 8 * hi);
  }

  // all-ones A fragment (bf16 1.0 = 0x3F80) for the row-sum MFMA
  const bf8_t onesA = __builtin_bit_cast(bf8_t,
      (u32x4){0x3F803F80u, 0x3F803F80u, 0x3F803F80u, 0x3F803F80u});

  f16v yacc[2];
  #pragma unroll
  for (int ot = 0; ot < 2; ++ot)
    #pragma unroll
    for (int r = 0; r < 16; ++r) yacc[ot][r] = 0.f;
  f16v y2;                       // row-sum accumulator; only y2[0] is consumed
  #pragma unroll
  for (int r = 0; r < 16; ++r) y2[r] = 0.f;
  float m_ = -1e30f;

  // ---- staging addresses (per thread: 2 phi chunks + 2 gt chunks of 16B) --
  const int pr  = tid >> 3, pc = tid & 7;
  const int go  = tid >> 4, gc = tid & 15;
  const u16* phA = phi_h + ((size_t)b * N_PIX + pr) * DD + pc * 8;
  const u16* gtA = gt_h + ((size_t)b * DD + go) * N_PIX + gc * 8;
  const int pO0 = pr * 64 + ((pc ^ (pr & 7)) << 3);
  const int pO1 = pO0 + 4096;
  const int gO0 = 8192 + go * 128 + ((gc ^ (go & 7)) << 3);
  const int gO1 = gO0 + 4096;

  uint4 v0, v1, v2, v3;
  #define LOADS(kb_) do {                                              \
    v0 = *(const uint4*)(phA + (size_t)(kb_) * 8192);                  \
    v1 = *(const uint4*)(phA + (size_t)(kb_) * 8192 + 4096);           \
    v2 = *(const uint4*)(gtA + (size_t)(kb_) * 128);                   \
    v3 = *(const uint4*)(gtA + (size_t)(kb_) * 128 + 32 * (size_t)N_PIX); \
  } while (0)
  #define WRITES(buf_) do {                                            \
    u16* base_ = smem + (buf_) * 16384;                                \
    *(uint4*)(base_ + pO0) = v0;                                       \
    *(uint4*)(base_ + pO1) = v1;                                       \
    *(uint4*)(base_ + gO0) = v2;                                       \
    *(uint4*)(base_ + gO1) = v3;                                       \
  } while (0)

  LOADS(0); WRITES(0);
  __syncthreads();

  const int prow  = 32 * mh + l31;
  const int pbase = prow * 64;
  const int pkey  = prow & 7;

  #pragma unroll 2
  for (int t = 0; t < NT; ++t) {
    const int cur = t & 1;
    if (t < NT - 1) LOADS(t + 1);
    const u16* pb = smem + cur * 16384;
    const u16* gb = pb + 8192;

    // ---- QK^T (swapped): ST[m][q], 4 x mfma32 over K=64 ------------------
    f16v st;
    #pragma unroll
    for (int r = 0; r < 16; ++r) st[r] = 0.f;
    __builtin_amdgcn_s_setprio(1);
    #pragma unroll
    for (int kk = 0; kk < 4; ++kk) {
      bf8_t a = *(const bf8_t*)(pb + pbase + (((2 * kk + hi) ^ pkey) << 3));
      st = mfma32(a, th[kk], st);
    }
    __builtin_amdgcn_s_setprio(0);

    // ---- max: max3 tree + cross-half shfl (verified) ---------------------
    float t0 = max3f(st[0],  st[1],  st[2]);
    float t1 = max3f(st[3],  st[4],  st[5]);
    float t2 = max3f(st[6],  st[7],  st[8]);
    float t3 = max3f(st[9],  st[10], st[11]);
    float t4 = max3f(st[12], st[13], st[14]);
    float pmax = fmaxf(max3f(t0, t1, t2), max3f(t3, t4, st[15]));
    pmax = fmaxf(pmax, __shfl_xor(pmax, 32));

    // ---- defer-max (T13): rescale only when running max grows > 2^8 ------
    if (!__all(pmax <= m_ + 8.f)) {
      float mn = fmaxf(m_, pmax);
      float sc = EXP2(m_ - mn);
      m_ = mn;
      y2[0] *= sc;                 // only y2[0] is ever read
      #pragma unroll
      for (int ot = 0; ot < 2; ++ot)
        #pragma unroll
        for (int r = 0; r < 16; ++r) yacc[ot][r] *= sc;
    }

    // ---- P = 2^(st - m) ---------------------------------------------------
    #pragma unroll
    for (int r = 0; r < 16; ++r) st[r] = EXP2(st[r] - m_);

    // ---- P -> PV B-fragments (hw cvt_pk + permlane swap, distinct) -------
    uint32_t c0 = pack2(st[0],  st[1]),  c1 = pack2(st[2],  st[3]);
    uint32_t c2 = pack2(st[4],  st[5]),  c3 = pack2(st[6],  st[7]);
    uint32_t c4 = pack2(st[8],  st[9]),  c5 = pack2(st[10], st[11]);
    uint32_t c6 = pack2(st[12], st[13]), c7 = pack2(st[14], st[15]);
    pl32swap(c0, c2); pl32swap(c1, c3);
    pl32swap(c4, c6); pl32swap(c5, c7);
    bf8_t pf0 = __builtin_bit_cast(bf8_t, (u32x4){c0, c1, c2, c3}); // m 0..15
    bf8_t pf1 = __builtin_bit_cast(bf8_t, (u32x4){c4, c5, c6, c7}); // m 16..31

    // ---- PV + row-sum: y^T[o][q] += gt[o][m].P^T[m][q]; y2 += 1.P^T ------
    __builtin_amdgcn_s_setprio(1);
    y2 = mfma32(onesA, pf0, y2);   // every row of y2 = sum_m P[m][q]
    y2 = mfma32(onesA, pf1, y2);
    #pragma unroll
    for (int ot = 0; ot < 2; ++ot) {
      int orow  = 32 * ot + l31;
      int obase = orow * 128;
      int okey  = orow & 7;
      bf8_t g0 = *(const bf8_t*)(gb + obase + ((((mh << 2) + hi)     ^ okey) << 3));
      yacc[ot] = mfma32(g0, pf0, yacc[ot]);
      bf8_t g1 = *(const bf8_t*)(gb + obase + ((((mh << 2) + 2 + hi) ^ okey) << 3));
      yacc[ot] = mfma32(g1, pf1, yacc[ot]);
    }
    __builtin_amdgcn_s_setprio(0);

    if (t < NT - 1) WRITES(cur ^ 1);
    __syncthreads();
  }
  #undef LOADS
  #undef WRITES

  // l_ = full m-slice row sum (halves already merged inside pf0/pf1)
  float l_ = y2[0];

  // ---- 4-way flash merge across m-slices (reuse smem) ---------------------
  // ypart: [0,16384) u16 ; ml: [16384,17408) ; y_lds: [17408, 22016) pitch 72
  #pragma unroll
  for (int ot = 0; ot < 2; ++ot)
    #pragma unroll
    for (int r = 0; r < 16; ++r) {
      int o = 32 * ot + (r & 3) + 8 * (r >> 2) + 4 * hi;
      smem[(((qg * 4 + mh) * 64 + o) << 5) + l31] = f2b(yacc[ot][r]);
    }
  float* ml = (float*)(smem + 16384);
  if (hi == 0) {
    ml[(qg * 4 + mh) * 64 + l31]      = m_;
    ml[(qg * 4 + mh) * 64 + 32 + l31] = l_;
  }
  __syncthreads();

  u16* y_lds = smem + 17408;   // [64 q][72 pitch] bf16
  {
    const int qg2 = tid >> 8;
    const int rem = tid & 255;
    const int qq  = rem & 31;
    const int og  = rem >> 5;
    float mi[4], li[4];
    #pragma unroll
    for (int i = 0; i < 4; ++i) {
      mi[i] = ml[(qg2 * 4 + i) * 64 + qq];
      li[i] = ml[(qg2 * 4 + i) * 64 + 32 + qq];
    }
    float M = fmaxf(fmaxf(mi[0], mi[1]), fmaxf(mi[2], mi[3]));
    float e[4], L = 0.f;
    #pragma unroll
    for (int i = 0; i < 4; ++i) { e[i] = EXP2(mi[i] - M); L += li[i] * e[i]; }
    float invL = 1.0f / L;
    float acc[8];
    #pragma unroll
    for (int oo = 0; oo < 8; ++oo) {
      int o = og * 8 + oo;
      float a = 0.f;
      #pragma unroll
      for (int i = 0; i < 4; ++i)
        a += b2f(smem[(((qg2 * 4 + i) * 64 + o) << 5) + qq]) * e[i];
      acc[oo] = a * invL;
    }
    uint4 ov;
    ov.x = pack2(acc[0], acc[1]);
    ov.y = pack2(acc[2], acc[3]);
    ov.z = pack2(acc[4], acc[5]);
    ov.w = pack2(acc[6], acc[7]);
    *(uint4*)(y_lds + (32 * qg2 + qq) * 72 + og * 8) = ov;   // LDS, not global
  }
  __syncthreads();

  // ---- fused out-projection: out[c][n0+q] = ow[c][:]·y[q][:] + ob[c] + x --
  {
    const int ct = w & 3;          // c base = 32*ct
    const int qt = w >> 2;         // q base = 32*qt
    f16v oacc;
    #pragma unroll
    for (int r = 0; r < 16; ++r) oacc[r] = 0.f;
    #pragma unroll
    for (int kk = 0; kk < 4; ++kk) {
      const float* wp = ow + (size_t)(32 * ct + l31) * DD + 16 * kk + 8 * hi;
      bf8_t av;
      #pragma unroll
      for (int j = 0; j < 8; ++j) av[j] = (short)f2b(wp[j]);
      bf8_t bv = *(const bf8_t*)(y_lds + (32 * qt + l31) * 72 + 16 * kk + 8 * hi);
      oacc = mfma32(av, bv, oacc);
    }
    #pragma unroll
    for (int r = 0; r < 16; ++r) {
      int c = 32 * ct + (r & 3) + 8 * (r >> 2) + 4 * hi;
      size_t gi = ((size_t)b * CH + c) * N_PIX + q0 + 32 * qt + l31;
      out[gi] = oacc[r] + ob[c] + x[gi];
    }
  }
}

extern "C" void kernel_launch(void* const* d_in, const int* in_sizes, int n_in,
                              void* d_out, int out_size, void* d_ws, size_t ws_size,
                              hipStream_t stream) {
  const float* x  = (const float*)d_in[0];
  const float* tw = (const float*)d_in[1];
  const float* tb = (const float*)d_in[2];
  const float* pw = (const float*)d_in[3];
  const float* pb = (const float*)d_in[4];
  const float* gw = (const float*)d_in[5];
  const float* gb = (const float*)d_in[6];
  const float* ow = (const float*)d_in[7];
  const float* ob = (const float*)d_in[8];
  float* out = (float*)d_out;

  const size_t sz = (size_t)NBATCH * N_PIX * DD;   // elems per bf16 tensor
  u16* theta_h = (u16*)d_ws;
  u16* phi_h   = theta_h + sz;
  u16* gt_h    = phi_h + sz;

  proj_kernel<<<512, 256, 0, stream>>>(x, tw, tb, pw, pb, gw, gb,
                                       theta_h, phi_h, gt_h);
  attn_kernel<<<512, 512, 0, stream>>>(theta_h, phi_h, gt_h, ow, ob, x, out);
}